// Round 1
// baseline (465.414 us; speedup 1.0000x reference)
//
#include <hip/hip_runtime.h>
#include <math.h>

#define DIM 128
#define KH 4

// ---------------- init: copy x -> X(d_out), zero hist & degcnt ----------------
__global__ __launch_bounds__(256) void k_init(const float4* __restrict__ xin,
                                              float4* __restrict__ X4,
                                              int* __restrict__ hist,
                                              int* __restrict__ degcnt,
                                              int n4, int N) {
  int i = blockIdx.x * 256 + threadIdx.x;
  if (i < n4) X4[i] = xin[i];
  if (i < N) hist[i] = 0;
  if (i < N * KH) degcnt[i] = 0;
}

// ---------------- count: per-dst histogram + per-(dst,k) degree ----------------
__global__ __launch_bounds__(256) void k_count(const int* __restrict__ ei,
                                               const int* __restrict__ attr,
                                               int* __restrict__ hist,
                                               int* __restrict__ degcnt, int E) {
  int e = blockIdx.x * 256 + threadIdx.x;
  if (e >= E) return;
  int dst = ei[E + e];
  int k = attr[e] - 1;
  atomicAdd(&hist[dst], 1);
  atomicAdd(&degcnt[dst * KH + k], 1);
}

// ---------------- 3-kernel exclusive scan ----------------
__global__ __launch_bounds__(256) void k_scan1(const int* __restrict__ in,
                                               int* __restrict__ out,
                                               int* __restrict__ bsum, int n) {
  __shared__ int s[256];
  int t = threadIdx.x;
  int i = blockIdx.x * 256 + t;
  int v = (i < n) ? in[i] : 0;
  s[t] = v;
  __syncthreads();
  for (int d = 1; d < 256; d <<= 1) {
    int u = (t >= d) ? s[t - d] : 0;
    __syncthreads();
    s[t] += u;
    __syncthreads();
  }
  if (i < n) out[i] = s[t] - v;          // exclusive
  if (t == 255) bsum[blockIdx.x] = s[255];
}

__global__ __launch_bounds__(256) void k_scan2(const int* __restrict__ bsum,
                                               int* __restrict__ bex, int nb) {
  __shared__ int s[256];
  int t = threadIdx.x;
  int v = (t < nb) ? bsum[t] : 0;
  s[t] = v;
  __syncthreads();
  for (int d = 1; d < 256; d <<= 1) {
    int u = (t >= d) ? s[t - d] : 0;
    __syncthreads();
    s[t] += u;
    __syncthreads();
  }
  if (t < nb) bex[t] = s[t] - v;
}

__global__ __launch_bounds__(256) void k_scan3(int* __restrict__ off,
                                               const int* __restrict__ bex,
                                               int* __restrict__ cursor, int n, int E) {
  int i = blockIdx.x * 256 + threadIdx.x;
  if (i < n) {
    int o = off[i] + bex[blockIdx.x];
    off[i] = o;
    cursor[i] = o;
  }
  if (i == 0) off[n] = E;
}

// ---------------- dinv = rsqrt(deg+1) ----------------
__global__ __launch_bounds__(256) void k_dinv(const int* __restrict__ degcnt,
                                              float* __restrict__ dinv, int n) {
  int i = blockIdx.x * 256 + threadIdx.x;
  if (i < n) dinv[i] = rsqrtf((float)degcnt[i] + 1.0f);
}

// ---------------- scatter edges into CSR order ----------------
__global__ __launch_bounds__(256) void k_scatter(const int* __restrict__ ei,
                                                 const int* __restrict__ attr,
                                                 const float* __restrict__ dinv,
                                                 int* __restrict__ cursor,
                                                 int* __restrict__ srck,
                                                 float* __restrict__ enorm, int E) {
  int e = blockIdx.x * 256 + threadIdx.x;
  if (e >= E) return;
  int src = ei[e];
  int dst = ei[E + e];
  int k = attr[e] - 1;
  int pos = atomicAdd(&cursor[dst], 1);
  srck[pos] = src | (k << 16);
  enorm[pos] = dinv[src * KH + k] * dinv[dst * KH + k];
}

// ---------------- GEMM: H = X(NxDIM) @ W(DIMxDIM), fp32 ----------------
#define FMA4(A, xc, wv)                 \
  A.x = fmaf(xc, wv.x, A.x);            \
  A.y = fmaf(xc, wv.y, A.y);            \
  A.z = fmaf(xc, wv.z, A.z);            \
  A.w = fmaf(xc, wv.w, A.w);

__global__ __launch_bounds__(256) void k_gemm(const float* __restrict__ X,
                                              const float* __restrict__ W,
                                              float* __restrict__ H, int N) {
  __shared__ float xs[64][64];    // 64 rows x 64 k-slice
  __shared__ float ws[64][128];   // 64 k-slice x 128 cols
  int t = threadIdx.x;
  int r0 = blockIdx.x * 64;
  int tc = t & 31;   // cols tc*4 .. tc*4+3
  int tr = t >> 5;   // rows tr*8 .. tr*8+7
  float4 acc[8];
#pragma unroll
  for (int i = 0; i < 8; ++i) acc[i] = make_float4(0.f, 0.f, 0.f, 0.f);

  for (int kb = 0; kb < 2; ++kb) {
    __syncthreads();
    // stage x tile: 64x64 = 1024 float4
#pragma unroll
    for (int i = 0; i < 4; ++i) {
      int fi = i * 256 + t;
      int kq = fi & 15, rr = fi >> 4;
      int row = r0 + rr;
      if (row >= N) row = N - 1;
      *(float4*)&xs[rr][kq * 4] =
          *(const float4*)&X[(size_t)row * DIM + kb * 64 + kq * 4];
    }
    // stage W k-half: 64x128 = 2048 float4
#pragma unroll
    for (int i = 0; i < 8; ++i) {
      int fi = i * 256 + t;
      int jq = fi & 31, kk = fi >> 5;
      *(float4*)&ws[kk][jq * 4] =
          *(const float4*)&W[(size_t)(kb * 64 + kk) * DIM + jq * 4];
    }
    __syncthreads();
#pragma unroll
    for (int k4 = 0; k4 < 16; ++k4) {
      float4 wv0 = *(float4*)&ws[k4 * 4 + 0][tc * 4];
      float4 wv1 = *(float4*)&ws[k4 * 4 + 1][tc * 4];
      float4 wv2 = *(float4*)&ws[k4 * 4 + 2][tc * 4];
      float4 wv3 = *(float4*)&ws[k4 * 4 + 3][tc * 4];
#pragma unroll
      for (int rr = 0; rr < 8; ++rr) {
        float4 xv = *(float4*)&xs[tr * 8 + rr][k4 * 4];
        FMA4(acc[rr], xv.x, wv0)
        FMA4(acc[rr], xv.y, wv1)
        FMA4(acc[rr], xv.z, wv2)
        FMA4(acc[rr], xv.w, wv3)
      }
    }
  }
#pragma unroll
  for (int rr = 0; rr < 8; ++rr) {
    int row = r0 + tr * 8 + rr;
    if (row < N) *(float4*)&H[(size_t)row * DIM + tc * 4] = acc[rr];
  }
}

// ---------------- aggregate + self-loop + bias + residual ReLU + L2 norm ----------------
__global__ __launch_bounds__(256) void k_agg(const int* __restrict__ off,
                                             const int* __restrict__ srck,
                                             const float* __restrict__ enorm,
                                             const float* __restrict__ dinv,
                                             const float* __restrict__ H,
                                             const float* __restrict__ bias,
                                             const float* __restrict__ alpha,
                                             float* __restrict__ X, int N) {
  int wid = threadIdx.x >> 6;
  int lane = threadIdx.x & 63;
  int n = blockIdx.x * 4 + wid;
  if (n >= N) return;

  // softmax over the 4 hop weights (tiny, recompute per wave)
  float a0 = alpha[0], a1 = alpha[1], a2 = alpha[2], a3 = alpha[3];
  float m = fmaxf(fmaxf(a0, a1), fmaxf(a2, a3));
  a0 = __expf(a0 - m); a1 = __expf(a1 - m); a2 = __expf(a2 - m); a3 = __expf(a3 - m);
  float is = 1.0f / (a0 + a1 + a2 + a3);
  a0 *= is; a1 *= is; a2 *= is; a3 *= is;

  int e0 = off[n], e1 = off[n + 1];
  const float2* H2 = (const float2*)H;
  float accx = 0.f, accy = 0.f;

  for (int base = e0; base < e1; base += 64) {
    int cnt = min(64, e1 - base);
    int sk = 0;
    float nm = 0.f;
    if (lane < cnt) {
      sk = srck[base + lane];
      nm = enorm[base + lane];
    }
    for (int j = 0; j < cnt; ++j) {
      int skj = __shfl(sk, j);
      float nmj = __shfl(nm, j);
      int s = skj & 0xFFFF;
      int k = skj >> 16;
      float ak = (k == 0) ? a0 : (k == 1) ? a1 : (k == 2) ? a2 : a3;
      float ww = ak * nmj;
      float2 hv = H2[(size_t)s * 64 + lane];
      accx = fmaf(ww, hv.x, accx);
      accy = fmaf(ww, hv.y, accy);
    }
  }

  // self-loop coefficient: sum_k a_k / deg = sum_k a_k * dinv^2
  float4 dv = *(const float4*)&dinv[n * 4];
  float sc = a0 * dv.x * dv.x + a1 * dv.y * dv.y + a2 * dv.z * dv.z + a3 * dv.w * dv.w;

  float2 hn = H2[(size_t)n * 64 + lane];
  float2 bb = ((const float2*)bias)[lane];
  float2 xo = ((const float2*)X)[(size_t)n * 64 + lane];
  float o0 = accx + sc * hn.x + bb.x;
  float o1 = accy + sc * hn.y + bb.y;
  float x0 = xo.x + fmaxf(o0, 0.f);
  float x1 = xo.y + fmaxf(o1, 0.f);

  float ss = x0 * x0 + x1 * x1;
#pragma unroll
  for (int d = 32; d; d >>= 1) ss += __shfl_xor(ss, d);
  float nrm = fmaxf(sqrtf(ss), 1e-12f);
  float inv = 1.0f / nrm;
  ((float2*)X)[(size_t)n * 64 + lane] = make_float2(x0 * inv, x1 * inv);
}

// ---------------- host launcher ----------------
extern "C" void kernel_launch(void* const* d_in, const int* in_sizes, int n_in,
                              void* d_out, int out_size, void* d_ws, size_t ws_size,
                              hipStream_t stream) {
  const float* x = (const float*)d_in[0];
  const int* ei = (const int*)d_in[1];
  const int* attr = (const int*)d_in[2];
  const float* W = (const float*)d_in[3];
  const float* b = (const float*)d_in[4];
  const float* alpha = (const float*)d_in[5];
  float* X = (float*)d_out;

  int N = in_sizes[0] / DIM;
  int E = in_sizes[1] / 2;
  int L = in_sizes[3] / (DIM * DIM);

  char* base = (char*)d_ws;
  size_t ofs = 0;
  auto carve = [&](size_t bytes) -> void* {
    void* p = base + ofs;
    ofs = (ofs + bytes + 255) & ~(size_t)255;
    return p;
  };
  int* off = (int*)carve((size_t)(N + 1) * 4);
  int* cursor = (int*)carve((size_t)N * 4);
  int* hist = (int*)carve((size_t)N * 4);
  int* degcnt = (int*)carve((size_t)N * KH * 4);
  float* dinv = (float*)carve((size_t)N * KH * 4);
  int* bsum = (int*)carve(256 * 4);
  int* bex = (int*)carve(256 * 4);
  int* srck = (int*)carve((size_t)E * 4);
  float* enorm = (float*)carve((size_t)E * 4);
  float* Hbuf = (float*)carve((size_t)N * DIM * 4);

  int n4 = N * DIM / 4;
  int nb = (N + 255) / 256;

  k_init<<<(n4 + 255) / 256, 256, 0, stream>>>((const float4*)x, (float4*)X,
                                               hist, degcnt, n4, N);
  k_count<<<(E + 255) / 256, 256, 0, stream>>>(ei, attr, hist, degcnt, E);
  k_scan1<<<nb, 256, 0, stream>>>(hist, off, bsum, N);
  k_scan2<<<1, 256, 0, stream>>>(bsum, bex, nb);
  k_scan3<<<nb, 256, 0, stream>>>(off, bex, cursor, N, E);
  k_dinv<<<(N * KH + 255) / 256, 256, 0, stream>>>(degcnt, dinv, N * KH);
  k_scatter<<<(E + 255) / 256, 256, 0, stream>>>(ei, attr, dinv, cursor, srck,
                                                 enorm, E);

  for (int t = 0; t < L; ++t) {
    k_gemm<<<(N + 63) / 64, 256, 0, stream>>>(X, W + (size_t)t * DIM * DIM, Hbuf, N);
    k_agg<<<(N + 3) / 4, 256, 0, stream>>>(off, srck, enorm, dinv, Hbuf,
                                           b + (size_t)t * DIM, alpha + (size_t)t * KH,
                                           X, N);
  }
}

// Round 2
// 369.541 us; speedup vs baseline: 1.2594x; 1.2594x over previous
//
#include <hip/hip_runtime.h>
#include <math.h>

#define DIM 128
#define KH 4

typedef unsigned int uint;
typedef unsigned short ushort;

// ---------------- init: copy x -> X(d_out), zero hist & degcnt ----------------
__global__ __launch_bounds__(256) void k_init(const float4* __restrict__ xin,
                                              float4* __restrict__ X4,
                                              int* __restrict__ hist,
                                              int* __restrict__ degcnt,
                                              int n4, int N) {
  int i = blockIdx.x * 256 + threadIdx.x;
  if (i < n4) X4[i] = xin[i];
  if (i < N) hist[i] = 0;
  if (i < N * KH) degcnt[i] = 0;
}

// ---------------- count: per-dst histogram + per-(dst,k) degree ----------------
__global__ __launch_bounds__(256) void k_count(const int* __restrict__ ei,
                                               const int* __restrict__ attr,
                                               int* __restrict__ hist,
                                               int* __restrict__ degcnt, int E) {
  int e = blockIdx.x * 256 + threadIdx.x;
  if (e >= E) return;
  int dst = ei[E + e];
  int k = attr[e] - 1;
  atomicAdd(&hist[dst], 1);
  atomicAdd(&degcnt[dst * KH + k], 1);
}

// ---------------- 3-kernel exclusive scan ----------------
__global__ __launch_bounds__(256) void k_scan1(const int* __restrict__ in,
                                               int* __restrict__ out,
                                               int* __restrict__ bsum, int n) {
  __shared__ int s[256];
  int t = threadIdx.x;
  int i = blockIdx.x * 256 + t;
  int v = (i < n) ? in[i] : 0;
  s[t] = v;
  __syncthreads();
  for (int d = 1; d < 256; d <<= 1) {
    int u = (t >= d) ? s[t - d] : 0;
    __syncthreads();
    s[t] += u;
    __syncthreads();
  }
  if (i < n) out[i] = s[t] - v;          // exclusive
  if (t == 255) bsum[blockIdx.x] = s[255];
}

__global__ __launch_bounds__(256) void k_scan2(const int* __restrict__ bsum,
                                               int* __restrict__ bex, int nb) {
  __shared__ int s[256];
  int t = threadIdx.x;
  int v = (t < nb) ? bsum[t] : 0;
  s[t] = v;
  __syncthreads();
  for (int d = 1; d < 256; d <<= 1) {
    int u = (t >= d) ? s[t - d] : 0;
    __syncthreads();
    s[t] += u;
    __syncthreads();
  }
  if (t < nb) bex[t] = s[t] - v;
}

__global__ __launch_bounds__(256) void k_scan3(int* __restrict__ off,
                                               const int* __restrict__ bex,
                                               int* __restrict__ cursor, int n, int E) {
  int i = blockIdx.x * 256 + threadIdx.x;
  if (i < n) {
    int o = off[i] + bex[blockIdx.x];
    off[i] = o;
    cursor[i] = o;
  }
  if (i == 0) off[n] = E;
}

// ---------------- dinv = rsqrt(deg+1) ----------------
__global__ __launch_bounds__(256) void k_dinv(const int* __restrict__ degcnt,
                                              float* __restrict__ dinv, int n) {
  int i = blockIdx.x * 256 + threadIdx.x;
  if (i < n) dinv[i] = rsqrtf((float)degcnt[i] + 1.0f);
}

// ---------------- scatter edges into CSR order ----------------
__global__ __launch_bounds__(256) void k_scatter(const int* __restrict__ ei,
                                                 const int* __restrict__ attr,
                                                 const float* __restrict__ dinv,
                                                 int* __restrict__ cursor,
                                                 int* __restrict__ srck,
                                                 float* __restrict__ enorm, int E) {
  int e = blockIdx.x * 256 + threadIdx.x;
  if (e >= E) return;
  int src = ei[e];
  int dst = ei[E + e];
  int k = attr[e] - 1;
  int pos = atomicAdd(&cursor[dst], 1);
  srck[pos] = src | (k << 16);   // src < 65536 (N=50000)
  enorm[pos] = dinv[src * KH + k] * dinv[dst * KH + k];
}

// fp32 -> bf16 round-to-nearest-even (bit trick, no NaN concern here)
__device__ __forceinline__ uint f2bf(float f) {
  uint u = __float_as_uint(f);
  return (u + 0x7fffu + ((u >> 16) & 1u)) >> 16;
}
__device__ __forceinline__ float bflo(uint u) { return __uint_as_float(u << 16); }
__device__ __forceinline__ float bfhi(uint u) { return __uint_as_float(u & 0xffff0000u); }

// ---------------- GEMM: H = X(NxDIM) @ W(DIMxDIM), fp32 math, bf16 out ----------------
#define FMA4(A, xc, wv)                 \
  A.x = fmaf(xc, wv.x, A.x);            \
  A.y = fmaf(xc, wv.y, A.y);            \
  A.z = fmaf(xc, wv.z, A.z);            \
  A.w = fmaf(xc, wv.w, A.w);

__global__ __launch_bounds__(256) void k_gemm(const float* __restrict__ X,
                                              const float* __restrict__ W,
                                              uint* __restrict__ Hb,  // bf16x2, 64 per row
                                              int N) {
  __shared__ float xs[64][64];    // 64 rows x 64 k-slice
  __shared__ float ws[64][128];   // 64 k-slice x 128 cols
  int t = threadIdx.x;
  int r0 = blockIdx.x * 64;
  int tc = t & 31;   // cols tc*4 .. tc*4+3
  int tr = t >> 5;   // rows tr*8 .. tr*8+7
  float4 acc[8];
#pragma unroll
  for (int i = 0; i < 8; ++i) acc[i] = make_float4(0.f, 0.f, 0.f, 0.f);

  for (int kb = 0; kb < 2; ++kb) {
    __syncthreads();
#pragma unroll
    for (int i = 0; i < 4; ++i) {
      int fi = i * 256 + t;
      int kq = fi & 15, rr = fi >> 4;
      int row = r0 + rr;
      if (row >= N) row = N - 1;
      *(float4*)&xs[rr][kq * 4] =
          *(const float4*)&X[(size_t)row * DIM + kb * 64 + kq * 4];
    }
#pragma unroll
    for (int i = 0; i < 8; ++i) {
      int fi = i * 256 + t;
      int jq = fi & 31, kk = fi >> 5;
      *(float4*)&ws[kk][jq * 4] =
          *(const float4*)&W[(size_t)(kb * 64 + kk) * DIM + jq * 4];
    }
    __syncthreads();
#pragma unroll
    for (int k4 = 0; k4 < 16; ++k4) {
      float4 wv0 = *(float4*)&ws[k4 * 4 + 0][tc * 4];
      float4 wv1 = *(float4*)&ws[k4 * 4 + 1][tc * 4];
      float4 wv2 = *(float4*)&ws[k4 * 4 + 2][tc * 4];
      float4 wv3 = *(float4*)&ws[k4 * 4 + 3][tc * 4];
#pragma unroll
      for (int rr = 0; rr < 8; ++rr) {
        float4 xv = *(float4*)&xs[tr * 8 + rr][k4 * 4];
        FMA4(acc[rr], xv.x, wv0)
        FMA4(acc[rr], xv.y, wv1)
        FMA4(acc[rr], xv.z, wv2)
        FMA4(acc[rr], xv.w, wv3)
      }
    }
  }
#pragma unroll
  for (int rr = 0; rr < 8; ++rr) {
    int row = r0 + tr * 8 + rr;
    if (row < N) {
      uint2 o;
      o.x = f2bf(acc[rr].x) | (f2bf(acc[rr].y) << 16);
      o.y = f2bf(acc[rr].z) | (f2bf(acc[rr].w) << 16);
      *(uint2*)&Hb[(size_t)row * 64 + tc * 2] = o;
    }
  }
}

// ---------------- aggregate + self-loop + bias + residual ReLU + L2 norm ----------------
__global__ __launch_bounds__(256) void k_agg(const int* __restrict__ off,
                                             const int* __restrict__ srck,
                                             const float* __restrict__ enorm,
                                             const float* __restrict__ dinv,
                                             const uint* __restrict__ Hb,
                                             const float* __restrict__ bias,
                                             const float* __restrict__ alpha,
                                             float* __restrict__ X, int N) {
  int wid = threadIdx.x >> 6;
  int lane = threadIdx.x & 63;
  int n = blockIdx.x * 4 + wid;
  if (n >= N) return;

  // softmax over the 4 hop weights
  float a0 = alpha[0], a1 = alpha[1], a2 = alpha[2], a3 = alpha[3];
  float m = fmaxf(fmaxf(a0, a1), fmaxf(a2, a3));
  a0 = __expf(a0 - m); a1 = __expf(a1 - m); a2 = __expf(a2 - m); a3 = __expf(a3 - m);
  float is = 1.0f / (a0 + a1 + a2 + a3);
  a0 *= is; a1 *= is; a2 *= is; a3 *= is;

  int e0 = off[n], e1 = off[n + 1];
  float accx = 0.f, accy = 0.f;

  for (int base = e0; base < e1; base += 64) {
    int cnt = min(64, e1 - base);
    int sofs = 0;        // pre-shifted row offset (uints)
    float wc = 0.f;      // combined weight a_k * norm_e
    if (lane < cnt) {
      int v = srck[base + lane];
      int k = v >> 16;
      float ak = (k == 0) ? a0 : (k == 1) ? a1 : (k == 2) ? a2 : a3;
      sofs = (v & 0xFFFF) << 6;
      wc = ak * enorm[base + lane];
    }
    int j = 0;
    for (; j + 4 <= cnt; j += 4) {
      int s0 = __shfl(sofs, j),     s1 = __shfl(sofs, j + 1);
      int s2 = __shfl(sofs, j + 2), s3 = __shfl(sofs, j + 3);
      float w0 = __shfl(wc, j),     w1 = __shfl(wc, j + 1);
      float w2 = __shfl(wc, j + 2), w3 = __shfl(wc, j + 3);
      uint u0 = Hb[s0 + lane];
      uint u1 = Hb[s1 + lane];
      uint u2 = Hb[s2 + lane];
      uint u3 = Hb[s3 + lane];
      accx = fmaf(w0, bflo(u0), accx); accy = fmaf(w0, bfhi(u0), accy);
      accx = fmaf(w1, bflo(u1), accx); accy = fmaf(w1, bfhi(u1), accy);
      accx = fmaf(w2, bflo(u2), accx); accy = fmaf(w2, bfhi(u2), accy);
      accx = fmaf(w3, bflo(u3), accx); accy = fmaf(w3, bfhi(u3), accy);
    }
    for (; j < cnt; ++j) {
      int sj = __shfl(sofs, j);
      float wj = __shfl(wc, j);
      uint uj = Hb[sj + lane];
      accx = fmaf(wj, bflo(uj), accx);
      accy = fmaf(wj, bfhi(uj), accy);
    }
  }

  // self-loop coefficient: sum_k a_k / deg = sum_k a_k * dinv^2
  float4 dv = *(const float4*)&dinv[n * 4];
  float sc = a0 * dv.x * dv.x + a1 * dv.y * dv.y + a2 * dv.z * dv.z + a3 * dv.w * dv.w;

  uint un = Hb[(size_t)n * 64 + lane];
  float2 bb = ((const float2*)bias)[lane];
  float2 xo = ((const float2*)X)[(size_t)n * 64 + lane];
  float o0 = accx + sc * bflo(un) + bb.x;
  float o1 = accy + sc * bfhi(un) + bb.y;
  float x0 = xo.x + fmaxf(o0, 0.f);
  float x1 = xo.y + fmaxf(o1, 0.f);

  float ss = x0 * x0 + x1 * x1;
#pragma unroll
  for (int d = 32; d; d >>= 1) ss += __shfl_xor(ss, d);
  float nrm = fmaxf(sqrtf(ss), 1e-12f);
  float inv = 1.0f / nrm;
  ((float2*)X)[(size_t)n * 64 + lane] = make_float2(x0 * inv, x1 * inv);
}

// ---------------- host launcher ----------------
extern "C" void kernel_launch(void* const* d_in, const int* in_sizes, int n_in,
                              void* d_out, int out_size, void* d_ws, size_t ws_size,
                              hipStream_t stream) {
  const float* x = (const float*)d_in[0];
  const int* ei = (const int*)d_in[1];
  const int* attr = (const int*)d_in[2];
  const float* W = (const float*)d_in[3];
  const float* b = (const float*)d_in[4];
  const float* alpha = (const float*)d_in[5];
  float* X = (float*)d_out;

  int N = in_sizes[0] / DIM;
  int E = in_sizes[1] / 2;
  int L = in_sizes[3] / (DIM * DIM);

  char* base = (char*)d_ws;
  size_t ofs = 0;
  auto carve = [&](size_t bytes) -> void* {
    void* p = base + ofs;
    ofs = (ofs + bytes + 255) & ~(size_t)255;
    return p;
  };
  int* off = (int*)carve((size_t)(N + 1) * 4);
  int* cursor = (int*)carve((size_t)N * 4);
  int* hist = (int*)carve((size_t)N * 4);
  int* degcnt = (int*)carve((size_t)N * KH * 4);
  float* dinv = (float*)carve((size_t)N * KH * 4);
  int* bsum = (int*)carve(256 * 4);
  int* bex = (int*)carve(256 * 4);
  int* srck = (int*)carve((size_t)E * 4);
  float* enorm = (float*)carve((size_t)E * 4);
  uint* Hb = (uint*)carve((size_t)N * 64 * 4);   // bf16 H: 128 cols = 64 uints/row

  int n4 = N * DIM / 4;
  int nb = (N + 255) / 256;

  k_init<<<(n4 + 255) / 256, 256, 0, stream>>>((const float4*)x, (float4*)X,
                                               hist, degcnt, n4, N);
  k_count<<<(E + 255) / 256, 256, 0, stream>>>(ei, attr, hist, degcnt, E);
  k_scan1<<<nb, 256, 0, stream>>>(hist, off, bsum, N);
  k_scan2<<<1, 256, 0, stream>>>(bsum, bex, nb);
  k_scan3<<<nb, 256, 0, stream>>>(off, bex, cursor, N, E);
  k_dinv<<<(N * KH + 255) / 256, 256, 0, stream>>>(degcnt, dinv, N * KH);
  k_scatter<<<(E + 255) / 256, 256, 0, stream>>>(ei, attr, dinv, cursor, srck,
                                                 enorm, E);

  for (int t = 0; t < L; ++t) {
    k_gemm<<<(N + 63) / 64, 256, 0, stream>>>(X, W + (size_t)t * DIM * DIM, Hb, N);
    k_agg<<<(N + 3) / 4, 256, 0, stream>>>(off, srck, enorm, dinv, Hb,
                                           b + (size_t)t * DIM, alpha + (size_t)t * KH,
                                           X, N);
  }
}

// Round 3
// 334.398 us; speedup vs baseline: 1.3918x; 1.1051x over previous
//
#include <hip/hip_runtime.h>
#include <hip/hip_fp16.h>
#include <math.h>

#define DIM 128
#define KH 4

typedef unsigned int uint;
typedef unsigned short ushort;

// ---------------- init: copy x -> X(d_out), zero degpack ----------------
__global__ __launch_bounds__(256) void k_init(const float4* __restrict__ xin,
                                              float4* __restrict__ X4,
                                              uint* __restrict__ degpack,
                                              int n4, int N) {
  int i = blockIdx.x * 256 + threadIdx.x;
  if (i < n4) X4[i] = xin[i];
  if (i < N) degpack[i] = 0;
}

// ---------------- count: packed per-(dst,k) degree, 1 atomic/edge ----------------
__global__ __launch_bounds__(256) void k_count(const int* __restrict__ ei,
                                               const int* __restrict__ attr,
                                               uint* __restrict__ degpack, int E) {
  int e = blockIdx.x * 256 + threadIdx.x;
  if (e >= E) return;
  int dst = ei[E + e];
  int k = attr[e] - 1;
  atomicAdd(&degpack[dst], 1u << (k * 8));
}

// ---------------- 3-kernel exclusive scan over per-node totals ----------------
__global__ __launch_bounds__(256) void k_scan1(const uint* __restrict__ degpack,
                                               int* __restrict__ off,
                                               int* __restrict__ bsum, int n) {
  __shared__ int s[256];
  int t = threadIdx.x;
  int i = blockIdx.x * 256 + t;
  int v = 0;
  if (i < n) {
    uint w = degpack[i];
    v = (w & 0xff) + ((w >> 8) & 0xff) + ((w >> 16) & 0xff) + (w >> 24);
  }
  s[t] = v;
  __syncthreads();
  for (int d = 1; d < 256; d <<= 1) {
    int u = (t >= d) ? s[t - d] : 0;
    __syncthreads();
    s[t] += u;
    __syncthreads();
  }
  if (i < n) off[i] = s[t] - v;          // exclusive
  if (t == 255) bsum[blockIdx.x] = s[255];
}

__global__ __launch_bounds__(256) void k_scan2(const int* __restrict__ bsum,
                                               int* __restrict__ bex, int nb) {
  __shared__ int s[256];
  int t = threadIdx.x;
  int v = (t < nb) ? bsum[t] : 0;
  s[t] = v;
  __syncthreads();
  for (int d = 1; d < 256; d <<= 1) {
    int u = (t >= d) ? s[t - d] : 0;
    __syncthreads();
    s[t] += u;
    __syncthreads();
  }
  if (t < nb) bex[t] = s[t] - v;
}

// finalize offsets, seed per-(dst,k) cursors, compute dinv
__global__ __launch_bounds__(256) void k_scan3(int* __restrict__ off,
                                               const int* __restrict__ bex,
                                               const uint* __restrict__ degpack,
                                               int* __restrict__ cursor4,
                                               float* __restrict__ dinv, int n) {
  int i = blockIdx.x * 256 + threadIdx.x;
  if (i >= n) return;
  int o = off[i] + bex[blockIdx.x];
  off[i] = o;
  uint w = degpack[i];
  int b0 = w & 0xff, b1 = (w >> 8) & 0xff, b2 = (w >> 16) & 0xff, b3 = w >> 24;
  int4 c;
  c.x = o;
  c.y = o + b0;
  c.z = o + b0 + b1;
  c.w = o + b0 + b1 + b2;
  *(int4*)&cursor4[i * 4] = c;
  float4 dv;
  dv.x = rsqrtf((float)b0 + 1.0f);
  dv.y = rsqrtf((float)b1 + 1.0f);
  dv.z = rsqrtf((float)b2 + 1.0f);
  dv.w = rsqrtf((float)b3 + 1.0f);
  *(float4*)&dinv[i * 4] = dv;
}

// ---------------- scatter: one 4B payload per edge, k-sorted within dst ----------------
__global__ __launch_bounds__(256) void k_scatter(const int* __restrict__ ei,
                                                 const int* __restrict__ attr,
                                                 const float* __restrict__ dinv,
                                                 int* __restrict__ cursor4,
                                                 uint* __restrict__ srcnm, int E) {
  int e = blockIdx.x * 256 + threadIdx.x;
  if (e >= E) return;
  int src = ei[e];
  int dst = ei[E + e];
  int k = attr[e] - 1;
  float nm = dinv[src * KH + k] * dinv[dst * KH + k];
  ushort h = __half_as_ushort(__float2half(nm));
  int pos = atomicAdd(&cursor4[dst * KH + k], 1);
  srcnm[pos] = (uint)src | ((uint)h << 16);   // src < 65536 (N=50000)
}

// fp32 -> bf16 round-to-nearest-even
__device__ __forceinline__ uint f2bf(float f) {
  uint u = __float_as_uint(f);
  return (u + 0x7fffu + ((u >> 16) & 1u)) >> 16;
}
__device__ __forceinline__ float bflo(uint u) { return __uint_as_float(u << 16); }
__device__ __forceinline__ float bfhi(uint u) { return __uint_as_float(u & 0xffff0000u); }

// ---------------- GEMM: H = X(NxDIM) @ W(DIMxDIM), fp32 math, bf16 out ----------------
#define FMA4(A, xc, wv)                 \
  A.x = fmaf(xc, wv.x, A.x);            \
  A.y = fmaf(xc, wv.y, A.y);            \
  A.z = fmaf(xc, wv.z, A.z);            \
  A.w = fmaf(xc, wv.w, A.w);

__global__ __launch_bounds__(256) void k_gemm(const float* __restrict__ X,
                                              const float* __restrict__ W,
                                              uint* __restrict__ Hb,  // bf16x2, 64/row
                                              int N) {
  __shared__ float xs[64][64];
  __shared__ float ws[64][128];
  int t = threadIdx.x;
  int r0 = blockIdx.x * 64;
  int tc = t & 31;
  int tr = t >> 5;
  float4 acc[8];
#pragma unroll
  for (int i = 0; i < 8; ++i) acc[i] = make_float4(0.f, 0.f, 0.f, 0.f);

  for (int kb = 0; kb < 2; ++kb) {
    __syncthreads();
#pragma unroll
    for (int i = 0; i < 4; ++i) {
      int fi = i * 256 + t;
      int kq = fi & 15, rr = fi >> 4;
      int row = r0 + rr;
      if (row >= N) row = N - 1;
      *(float4*)&xs[rr][kq * 4] =
          *(const float4*)&X[(size_t)row * DIM + kb * 64 + kq * 4];
    }
#pragma unroll
    for (int i = 0; i < 8; ++i) {
      int fi = i * 256 + t;
      int jq = fi & 31, kk = fi >> 5;
      *(float4*)&ws[kk][jq * 4] =
          *(const float4*)&W[(size_t)(kb * 64 + kk) * DIM + jq * 4];
    }
    __syncthreads();
#pragma unroll
    for (int k4 = 0; k4 < 16; ++k4) {
      float4 wv0 = *(float4*)&ws[k4 * 4 + 0][tc * 4];
      float4 wv1 = *(float4*)&ws[k4 * 4 + 1][tc * 4];
      float4 wv2 = *(float4*)&ws[k4 * 4 + 2][tc * 4];
      float4 wv3 = *(float4*)&ws[k4 * 4 + 3][tc * 4];
#pragma unroll
      for (int rr = 0; rr < 8; ++rr) {
        float4 xv = *(float4*)&xs[tr * 8 + rr][k4 * 4];
        FMA4(acc[rr], xv.x, wv0)
        FMA4(acc[rr], xv.y, wv1)
        FMA4(acc[rr], xv.z, wv2)
        FMA4(acc[rr], xv.w, wv3)
      }
    }
  }
#pragma unroll
  for (int rr = 0; rr < 8; ++rr) {
    int row = r0 + tr * 8 + rr;
    if (row < N) {
      uint2 o;
      o.x = f2bf(acc[rr].x) | (f2bf(acc[rr].y) << 16);
      o.y = f2bf(acc[rr].z) | (f2bf(acc[rr].w) << 16);
      *(uint2*)&Hb[(size_t)row * 64 + tc * 2] = o;
    }
  }
}

// ---------------- aggregate + self-loop + bias + residual ReLU + L2 norm ----------------
__global__ __launch_bounds__(256) void k_agg(const int* __restrict__ off,
                                             const uint* __restrict__ degpack,
                                             const uint* __restrict__ srcnm,
                                             const float* __restrict__ dinv,
                                             const uint* __restrict__ Hb,
                                             const float* __restrict__ bias,
                                             const float* __restrict__ alpha,
                                             float* __restrict__ X, int N) {
  int wid = threadIdx.x >> 6;
  int lane = threadIdx.x & 63;
  int n = blockIdx.x * 4 + wid;
  if (n >= N) return;

  // softmax over the 4 hop weights
  float a0 = alpha[0], a1 = alpha[1], a2 = alpha[2], a3 = alpha[3];
  float m = fmaxf(fmaxf(a0, a1), fmaxf(a2, a3));
  a0 = __expf(a0 - m); a1 = __expf(a1 - m); a2 = __expf(a2 - m); a3 = __expf(a3 - m);
  float is = 1.0f / (a0 + a1 + a2 + a3);
  a0 *= is; a1 *= is; a2 *= is; a3 *= is;

  uint w = degpack[n];
  int b0 = w & 0xff, b1 = (w >> 8) & 0xff, b2 = (w >> 16) & 0xff, b3 = (int)(w >> 24);
  int e0 = off[n];
  int e1 = e0 + b0 + b1 + b2 + b3;
  int k1 = e0 + b0, k2 = k1 + b1, k3 = k2 + b2;

  float accx = 0.f, accy = 0.f;

  for (int base = e0; base < e1; base += 64) {
    int cnt = min(64, e1 - base);
    int sofs = 0;
    float wc = 0.f;
    if (lane < cnt) {
      uint v = srcnm[base + lane];
      int pos = base + lane;
      int k = (pos >= k1) + (pos >= k2) + (pos >= k3);
      float ak = (k == 0) ? a0 : (k == 1) ? a1 : (k == 2) ? a2 : a3;
      wc = ak * __half2float(__ushort_as_half((ushort)(v >> 16)));
      sofs = (int)(v & 0xFFFFu) << 6;
    }
    int j = 0;
    for (; j + 4 <= cnt; j += 4) {
      int s0 = __shfl(sofs, j),     s1 = __shfl(sofs, j + 1);
      int s2 = __shfl(sofs, j + 2), s3 = __shfl(sofs, j + 3);
      float w0 = __shfl(wc, j),     w1 = __shfl(wc, j + 1);
      float w2 = __shfl(wc, j + 2), w3 = __shfl(wc, j + 3);
      uint u0 = Hb[s0 + lane];
      uint u1 = Hb[s1 + lane];
      uint u2 = Hb[s2 + lane];
      uint u3 = Hb[s3 + lane];
      accx = fmaf(w0, bflo(u0), accx); accy = fmaf(w0, bfhi(u0), accy);
      accx = fmaf(w1, bflo(u1), accx); accy = fmaf(w1, bfhi(u1), accy);
      accx = fmaf(w2, bflo(u2), accx); accy = fmaf(w2, bfhi(u2), accy);
      accx = fmaf(w3, bflo(u3), accx); accy = fmaf(w3, bfhi(u3), accy);
    }
    for (; j < cnt; ++j) {
      int sj = __shfl(sofs, j);
      float wj = __shfl(wc, j);
      uint uj = Hb[sj + lane];
      accx = fmaf(wj, bflo(uj), accx);
      accy = fmaf(wj, bfhi(uj), accy);
    }
  }

  // self-loop coefficient: sum_k a_k * dinv^2
  float4 dv = *(const float4*)&dinv[n * 4];
  float sc = a0 * dv.x * dv.x + a1 * dv.y * dv.y + a2 * dv.z * dv.z + a3 * dv.w * dv.w;

  uint un = Hb[(size_t)n * 64 + lane];
  float2 bb = ((const float2*)bias)[lane];
  float2 xo = ((const float2*)X)[(size_t)n * 64 + lane];
  float o0 = accx + sc * bflo(un) + bb.x;
  float o1 = accy + sc * bfhi(un) + bb.y;
  float x0 = xo.x + fmaxf(o0, 0.f);
  float x1 = xo.y + fmaxf(o1, 0.f);

  float ss = x0 * x0 + x1 * x1;
#pragma unroll
  for (int d = 32; d; d >>= 1) ss += __shfl_xor(ss, d);
  float nrm = fmaxf(sqrtf(ss), 1e-12f);
  float inv = 1.0f / nrm;
  ((float2*)X)[(size_t)n * 64 + lane] = make_float2(x0 * inv, x1 * inv);
}

// ---------------- host launcher ----------------
extern "C" void kernel_launch(void* const* d_in, const int* in_sizes, int n_in,
                              void* d_out, int out_size, void* d_ws, size_t ws_size,
                              hipStream_t stream) {
  const float* x = (const float*)d_in[0];
  const int* ei = (const int*)d_in[1];
  const int* attr = (const int*)d_in[2];
  const float* W = (const float*)d_in[3];
  const float* b = (const float*)d_in[4];
  const float* alpha = (const float*)d_in[5];
  float* X = (float*)d_out;

  int N = in_sizes[0] / DIM;
  int E = in_sizes[1] / 2;
  int L = in_sizes[3] / (DIM * DIM);

  char* base = (char*)d_ws;
  size_t ofs = 0;
  auto carve = [&](size_t bytes) -> void* {
    void* p = base + ofs;
    ofs = (ofs + bytes + 255) & ~(size_t)255;
    return p;
  };
  int* off = (int*)carve((size_t)(N + 1) * 4);
  int* cursor4 = (int*)carve((size_t)N * KH * 4);
  uint* degpack = (uint*)carve((size_t)N * 4);
  float* dinv = (float*)carve((size_t)N * KH * 4);
  int* bsum = (int*)carve(256 * 4);
  int* bex = (int*)carve(256 * 4);
  uint* srcnm = (uint*)carve((size_t)E * 4);
  uint* Hb = (uint*)carve((size_t)N * 64 * 4);

  int n4 = N * DIM / 4;
  int nb = (N + 255) / 256;

  k_init<<<(n4 + 255) / 256, 256, 0, stream>>>((const float4*)x, (float4*)X,
                                               degpack, n4, N);
  k_count<<<(E + 255) / 256, 256, 0, stream>>>(ei, attr, degpack, E);
  k_scan1<<<nb, 256, 0, stream>>>(degpack, off, bsum, N);
  k_scan2<<<1, 256, 0, stream>>>(bsum, bex, nb);
  k_scan3<<<nb, 256, 0, stream>>>(off, bex, degpack, cursor4, dinv, N);
  k_scatter<<<(E + 255) / 256, 256, 0, stream>>>(ei, attr, dinv, cursor4, srcnm, E);

  for (int t = 0; t < L; ++t) {
    k_gemm<<<(N + 63) / 64, 256, 0, stream>>>(X, W + (size_t)t * DIM * DIM, Hb, N);
    k_agg<<<(N + 3) / 4, 256, 0, stream>>>(off, degpack, srcnm, dinv, Hb,
                                           b + (size_t)t * DIM, alpha + (size_t)t * KH,
                                           X, N);
  }
}

// Round 4
// 318.374 us; speedup vs baseline: 1.4618x; 1.0503x over previous
//
#include <hip/hip_runtime.h>
#include <hip/hip_fp16.h>
#include <math.h>

#define DIM 128
#define KH 4

typedef unsigned int uint;
typedef unsigned short ushort;
using short8v = __attribute__((ext_vector_type(8))) short;
using f32x4 = __attribute__((ext_vector_type(4))) float;

// fp32 -> bf16 round-to-nearest-even
__device__ __forceinline__ uint f2bf(float f) {
  uint u = __float_as_uint(f);
  return (u + 0x7fffu + ((u >> 16) & 1u)) >> 16;
}
__device__ __forceinline__ float bf2f(uint u) { return __uint_as_float(u << 16); }
__device__ __forceinline__ float bflo(uint u) { return __uint_as_float(u << 16); }
__device__ __forceinline__ float bfhi(uint u) { return __uint_as_float(u & 0xffff0000u); }

// ---------------- init: copy x -> X(d_out), write Xhi/Xlo, zero degpack ----------------
__global__ __launch_bounds__(256) void k_init(const float4* __restrict__ xin,
                                              float4* __restrict__ X4,
                                              uint* __restrict__ Xhi,
                                              uint* __restrict__ Xlo,
                                              uint* __restrict__ degpack,
                                              int n4, int N) {
  int i = blockIdx.x * 256 + threadIdx.x;
  if (i < n4) {
    float4 v = xin[i];
    X4[i] = v;
    uint h0 = f2bf(v.x), h1 = f2bf(v.y), h2 = f2bf(v.z), h3 = f2bf(v.w);
    Xhi[i * 2 + 0] = h0 | (h1 << 16);
    Xhi[i * 2 + 1] = h2 | (h3 << 16);
    uint l0 = f2bf(v.x - bf2f(h0)), l1 = f2bf(v.y - bf2f(h1));
    uint l2 = f2bf(v.z - bf2f(h2)), l3 = f2bf(v.w - bf2f(h3));
    Xlo[i * 2 + 0] = l0 | (l1 << 16);
    Xlo[i * 2 + 1] = l2 | (l3 << 16);
  }
  if (i < N) degpack[i] = 0;
}

// ---------------- W prep: split into bf16 hi/lo, transposed [col][k] ----------------
__global__ __launch_bounds__(256) void k_wprep(const float* __restrict__ W,
                                               short* __restrict__ Whi,
                                               short* __restrict__ Wlo, int total) {
  int idx = blockIdx.x * 256 + threadIdx.x;
  if (idx >= total) return;
  int l = idx >> 14;          // layer
  int rem = idx & 16383;
  int k = rem >> 7;           // row of W (k index)
  int n = rem & 127;          // col of W
  float w = W[idx];
  uint h = f2bf(w);
  uint lo = f2bf(w - bf2f(h));
  size_t o = (size_t)l * 16384 + (size_t)n * 128 + k;   // [layer][col][k]
  Whi[o] = (short)h;
  Wlo[o] = (short)lo;
}

// ---------------- count: packed per-(dst,k) degree, 1 atomic/edge ----------------
__global__ __launch_bounds__(256) void k_count(const int* __restrict__ ei,
                                               const int* __restrict__ attr,
                                               uint* __restrict__ degpack, int E) {
  int e = blockIdx.x * 256 + threadIdx.x;
  if (e >= E) return;
  int dst = ei[E + e];
  int k = attr[e] - 1;
  atomicAdd(&degpack[dst], 1u << (k * 8));
}

// ---------------- 3-kernel exclusive scan over per-node totals ----------------
__global__ __launch_bounds__(256) void k_scan1(const uint* __restrict__ degpack,
                                               int* __restrict__ off,
                                               int* __restrict__ bsum, int n) {
  __shared__ int s[256];
  int t = threadIdx.x;
  int i = blockIdx.x * 256 + t;
  int v = 0;
  if (i < n) {
    uint w = degpack[i];
    v = (w & 0xff) + ((w >> 8) & 0xff) + ((w >> 16) & 0xff) + (w >> 24);
  }
  s[t] = v;
  __syncthreads();
  for (int d = 1; d < 256; d <<= 1) {
    int u = (t >= d) ? s[t - d] : 0;
    __syncthreads();
    s[t] += u;
    __syncthreads();
  }
  if (i < n) off[i] = s[t] - v;
  if (t == 255) bsum[blockIdx.x] = s[255];
}

__global__ __launch_bounds__(256) void k_scan2(const int* __restrict__ bsum,
                                               int* __restrict__ bex, int nb) {
  __shared__ int s[256];
  int t = threadIdx.x;
  int v = (t < nb) ? bsum[t] : 0;
  s[t] = v;
  __syncthreads();
  for (int d = 1; d < 256; d <<= 1) {
    int u = (t >= d) ? s[t - d] : 0;
    __syncthreads();
    s[t] += u;
    __syncthreads();
  }
  if (t < nb) bex[t] = s[t] - v;
}

__global__ __launch_bounds__(256) void k_scan3(int* __restrict__ off,
                                               const int* __restrict__ bex,
                                               const uint* __restrict__ degpack,
                                               int* __restrict__ cursor4,
                                               float* __restrict__ dinv, int n) {
  int i = blockIdx.x * 256 + threadIdx.x;
  if (i >= n) return;
  int o = off[i] + bex[blockIdx.x];
  off[i] = o;
  uint w = degpack[i];
  int b0 = w & 0xff, b1 = (w >> 8) & 0xff, b2 = (w >> 16) & 0xff, b3 = w >> 24;
  int4 c;
  c.x = o;
  c.y = o + b0;
  c.z = o + b0 + b1;
  c.w = o + b0 + b1 + b2;
  *(int4*)&cursor4[i * 4] = c;
  float4 dv;
  dv.x = rsqrtf((float)b0 + 1.0f);
  dv.y = rsqrtf((float)b1 + 1.0f);
  dv.z = rsqrtf((float)b2 + 1.0f);
  dv.w = rsqrtf((float)b3 + 1.0f);
  *(float4*)&dinv[i * 4] = dv;
}

// ---------------- scatter: one 4B payload per edge, k-sorted within dst ----------------
__global__ __launch_bounds__(256) void k_scatter(const int* __restrict__ ei,
                                                 const int* __restrict__ attr,
                                                 const float* __restrict__ dinv,
                                                 int* __restrict__ cursor4,
                                                 uint* __restrict__ srcnm, int E) {
  int e = blockIdx.x * 256 + threadIdx.x;
  if (e >= E) return;
  int src = ei[e];
  int dst = ei[E + e];
  int k = attr[e] - 1;
  float nm = dinv[src * KH + k] * dinv[dst * KH + k];
  ushort h = __half_as_ushort(__float2half(nm));
  int pos = atomicAdd(&cursor4[dst * KH + k], 1);
  srcnm[pos] = (uint)src | ((uint)h << 16);
}

// ---------------- GEMM via split-bf16 MFMA: H = X @ W, bf16 out ----------------
// Block: 512 threads = 8 waves (2 row x 4 col), tile 64 rows x 128 cols.
// acc = Xhi*Whi + Xlo*Whi + Xhi*Wlo  (~fp32 accuracy)
__global__ __launch_bounds__(512) void k_gemm(const uint* __restrict__ Xhi,
                                              const uint* __restrict__ Xlo,
                                              const short* __restrict__ Whi, // [col][k]
                                              const short* __restrict__ Wlo,
                                              ushort* __restrict__ Hb16, int N) {
  __shared__ __align__(16) short xs_hi[64 * 128];
  __shared__ __align__(16) short xs_lo[64 * 128];
  int t = threadIdx.x;
  int r0 = blockIdx.x * 64;

  // stage X tile (hi/lo), swizzled: 16B slot s at row r stored at s^(r&7)
#pragma unroll
  for (int i = 0; i < 2; ++i) {
    int fi = i * 512 + t;            // 0..1023
    int row = fi >> 4, kq = fi & 15;
    int rg = r0 + row;
    if (rg >= N) rg = N - 1;
    int swz = kq ^ (row & 7);
    *(uint4*)&xs_hi[row * 128 + swz * 8] = *(const uint4*)&Xhi[(size_t)rg * 64 + kq * 4];
    *(uint4*)&xs_lo[row * 128 + swz * 8] = *(const uint4*)&Xlo[(size_t)rg * 64 + kq * 4];
  }
  __syncthreads();

  int wid = t >> 6, lane = t & 63;
  int wrow = wid & 1, wcol = wid >> 1;   // 2 x 4 waves
  int lr = lane & 15, lk = lane >> 4;    // lk in 0..3

  f32x4 acc[2][2];
#pragma unroll
  for (int a = 0; a < 2; ++a)
#pragma unroll
    for (int c = 0; c < 2; ++c) acc[a][c] = (f32x4){0.f, 0.f, 0.f, 0.f};

#pragma unroll
  for (int ks = 0; ks < 4; ++ks) {
    int k0 = ks * 32 + lk * 8;
    short8v ah[2], al[2];
#pragma unroll
    for (int rt = 0; rt < 2; ++rt) {
      int r = wrow * 32 + rt * 16 + lr;
      int slot = (k0 >> 3) ^ (r & 7);
      ah[rt] = *(short8v*)&xs_hi[r * 128 + slot * 8];
      al[rt] = *(short8v*)&xs_lo[r * 128 + slot * 8];
    }
    short8v bh[2], bl[2];
#pragma unroll
    for (int ct = 0; ct < 2; ++ct) {
      int col = wcol * 32 + ct * 16 + lr;
      bh[ct] = *(const short8v*)&Whi[(size_t)col * 128 + k0];
      bl[ct] = *(const short8v*)&Wlo[(size_t)col * 128 + k0];
    }
#pragma unroll
    for (int rt = 0; rt < 2; ++rt)
#pragma unroll
      for (int ct = 0; ct < 2; ++ct) {
        acc[rt][ct] = __builtin_amdgcn_mfma_f32_16x16x32_bf16(ah[rt], bh[ct], acc[rt][ct], 0, 0, 0);
        acc[rt][ct] = __builtin_amdgcn_mfma_f32_16x16x32_bf16(al[rt], bh[ct], acc[rt][ct], 0, 0, 0);
        acc[rt][ct] = __builtin_amdgcn_mfma_f32_16x16x32_bf16(ah[rt], bl[ct], acc[rt][ct], 0, 0, 0);
      }
  }

  // epilogue: D[row=(lane>>4)*4+i][col=lane&15] per 16x16 tile
#pragma unroll
  for (int rt = 0; rt < 2; ++rt)
#pragma unroll
    for (int ct = 0; ct < 2; ++ct) {
      int col = wcol * 32 + ct * 16 + lr;
#pragma unroll
      for (int i = 0; i < 4; ++i) {
        int row = r0 + wrow * 32 + rt * 16 + lk * 4 + i;
        if (row < N) Hb16[(size_t)row * 128 + col] = (ushort)f2bf(acc[rt][ct][i]);
      }
    }
}

// ---------------- aggregate + self-loop + bias + residual ReLU + L2 norm ----------------
__global__ __launch_bounds__(256) void k_agg(const int* __restrict__ off,
                                             const uint* __restrict__ degpack,
                                             const uint* __restrict__ srcnm,
                                             const float* __restrict__ dinv,
                                             const uint* __restrict__ Hb,
                                             const float* __restrict__ bias,
                                             const float* __restrict__ alpha,
                                             float* __restrict__ X,
                                             uint* __restrict__ Xhi,
                                             uint* __restrict__ Xlo, int N) {
  int wid = threadIdx.x >> 6;
  int lane = threadIdx.x & 63;
  int n = blockIdx.x * 4 + wid;
  if (n >= N) return;

  float a0 = alpha[0], a1 = alpha[1], a2 = alpha[2], a3 = alpha[3];
  float m = fmaxf(fmaxf(a0, a1), fmaxf(a2, a3));
  a0 = __expf(a0 - m); a1 = __expf(a1 - m); a2 = __expf(a2 - m); a3 = __expf(a3 - m);
  float is = 1.0f / (a0 + a1 + a2 + a3);
  a0 *= is; a1 *= is; a2 *= is; a3 *= is;

  uint w = degpack[n];
  int b0 = w & 0xff, b1 = (w >> 8) & 0xff, b2 = (w >> 16) & 0xff, b3 = (int)(w >> 24);
  int e0 = off[n];
  int e1 = e0 + b0 + b1 + b2 + b3;
  int k1 = e0 + b0, k2 = k1 + b1, k3 = k2 + b2;

  float accx = 0.f, accy = 0.f;

  for (int base = e0; base < e1; base += 64) {
    int cnt = min(64, e1 - base);
    int sofs = 0;
    float wc = 0.f;
    if (lane < cnt) {
      uint v = srcnm[base + lane];
      int pos = base + lane;
      int k = (pos >= k1) + (pos >= k2) + (pos >= k3);
      float ak = (k == 0) ? a0 : (k == 1) ? a1 : (k == 2) ? a2 : a3;
      wc = ak * __half2float(__ushort_as_half((ushort)(v >> 16)));
      sofs = (int)(v & 0xFFFFu) << 6;
    }
    int j = 0;
    for (; j + 4 <= cnt; j += 4) {
      int s0 = __shfl(sofs, j),     s1 = __shfl(sofs, j + 1);
      int s2 = __shfl(sofs, j + 2), s3 = __shfl(sofs, j + 3);
      float w0 = __shfl(wc, j),     w1 = __shfl(wc, j + 1);
      float w2 = __shfl(wc, j + 2), w3 = __shfl(wc, j + 3);
      uint u0 = Hb[s0 + lane];
      uint u1 = Hb[s1 + lane];
      uint u2 = Hb[s2 + lane];
      uint u3 = Hb[s3 + lane];
      accx = fmaf(w0, bflo(u0), accx); accy = fmaf(w0, bfhi(u0), accy);
      accx = fmaf(w1, bflo(u1), accx); accy = fmaf(w1, bfhi(u1), accy);
      accx = fmaf(w2, bflo(u2), accx); accy = fmaf(w2, bfhi(u2), accy);
      accx = fmaf(w3, bflo(u3), accx); accy = fmaf(w3, bfhi(u3), accy);
    }
    for (; j < cnt; ++j) {
      int sj = __shfl(sofs, j);
      float wj = __shfl(wc, j);
      uint uj = Hb[sj + lane];
      accx = fmaf(wj, bflo(uj), accx);
      accy = fmaf(wj, bfhi(uj), accy);
    }
  }

  float4 dv = *(const float4*)&dinv[n * 4];
  float sc = a0 * dv.x * dv.x + a1 * dv.y * dv.y + a2 * dv.z * dv.z + a3 * dv.w * dv.w;

  uint un = Hb[(size_t)n * 64 + lane];
  float2 bb = ((const float2*)bias)[lane];
  float2 xo = ((const float2*)X)[(size_t)n * 64 + lane];
  float o0 = accx + sc * bflo(un) + bb.x;
  float o1 = accy + sc * bfhi(un) + bb.y;
  float x0 = xo.x + fmaxf(o0, 0.f);
  float x1 = xo.y + fmaxf(o1, 0.f);

  float ss = x0 * x0 + x1 * x1;
#pragma unroll
  for (int d = 32; d; d >>= 1) ss += __shfl_xor(ss, d);
  float nrm = fmaxf(sqrtf(ss), 1e-12f);
  float inv = 1.0f / nrm;
  float y0 = x0 * inv, y1 = x1 * inv;
  ((float2*)X)[(size_t)n * 64 + lane] = make_float2(y0, y1);

  // hi/lo bf16 split for next layer's MFMA GEMM
  uint h0 = f2bf(y0), h1 = f2bf(y1);
  Xhi[(size_t)n * 64 + lane] = h0 | (h1 << 16);
  uint l0 = f2bf(y0 - bf2f(h0)), l1 = f2bf(y1 - bf2f(h1));
  Xlo[(size_t)n * 64 + lane] = l0 | (l1 << 16);
}

// ---------------- host launcher ----------------
extern "C" void kernel_launch(void* const* d_in, const int* in_sizes, int n_in,
                              void* d_out, int out_size, void* d_ws, size_t ws_size,
                              hipStream_t stream) {
  const float* x = (const float*)d_in[0];
  const int* ei = (const int*)d_in[1];
  const int* attr = (const int*)d_in[2];
  const float* W = (const float*)d_in[3];
  const float* b = (const float*)d_in[4];
  const float* alpha = (const float*)d_in[5];
  float* X = (float*)d_out;

  int N = in_sizes[0] / DIM;
  int E = in_sizes[1] / 2;
  int L = in_sizes[3] / (DIM * DIM);

  char* base = (char*)d_ws;
  size_t ofs = 0;
  auto carve = [&](size_t bytes) -> void* {
    void* p = base + ofs;
    ofs = (ofs + bytes + 255) & ~(size_t)255;
    return p;
  };
  int* off = (int*)carve((size_t)(N + 1) * 4);
  int* cursor4 = (int*)carve((size_t)N * KH * 4);
  uint* degpack = (uint*)carve((size_t)N * 4);
  float* dinv = (float*)carve((size_t)N * KH * 4);
  int* bsum = (int*)carve(256 * 4);
  int* bex = (int*)carve(256 * 4);
  uint* srcnm = (uint*)carve((size_t)E * 4);
  uint* Hb = (uint*)carve((size_t)N * 64 * 4);
  uint* Xhi = (uint*)carve((size_t)N * 64 * 4);
  uint* Xlo = (uint*)carve((size_t)N * 64 * 4);
  short* Whi = (short*)carve((size_t)L * DIM * DIM * 2);
  short* Wlo = (short*)carve((size_t)L * DIM * DIM * 2);

  int n4 = N * DIM / 4;
  int nb = (N + 255) / 256;
  int wtot = L * DIM * DIM;

  k_init<<<(n4 + 255) / 256, 256, 0, stream>>>((const float4*)x, (float4*)X,
                                               Xhi, Xlo, degpack, n4, N);
  k_count<<<(E + 255) / 256, 256, 0, stream>>>(ei, attr, degpack, E);
  k_scan1<<<nb, 256, 0, stream>>>(degpack, off, bsum, N);
  k_scan2<<<1, 256, 0, stream>>>(bsum, bex, nb);
  k_scan3<<<nb, 256, 0, stream>>>(off, bex, degpack, cursor4, dinv, N);
  k_scatter<<<(E + 255) / 256, 256, 0, stream>>>(ei, attr, dinv, cursor4, srcnm, E);
  k_wprep<<<(wtot + 255) / 256, 256, 0, stream>>>(W, Whi, Wlo, wtot);

  for (int t = 0; t < L; ++t) {
    k_gemm<<<(N + 63) / 64, 512, 0, stream>>>(Xhi, Xlo,
                                              Whi + (size_t)t * DIM * DIM,
                                              Wlo + (size_t)t * DIM * DIM,
                                              (ushort*)Hb, N);
    k_agg<<<(N + 3) / 4, 256, 0, stream>>>(off, degpack, srcnm, dinv, Hb,
                                           b + (size_t)t * DIM, alpha + (size_t)t * KH,
                                           X, Xhi, Xlo, N);
  }
}